// Round 1
// baseline (262.021 us; speedup 1.0000x reference)
//
#include <hip/hip_runtime.h>

// DualTimeConstantHighPassMixAdaptation on MI355X (gfx950)
// x: [B=8, C=64, T=64000] fp32. 512 independent dual-EMA scans along T.
//
// Decomposition: EMA m[t] = a*m[t-1] + mu*y[t] is an affine recurrence.
// Per row: 1 block of 256 threads, 10 tiles of 6400 elements, each thread
// owns 25 contiguous elements. Two-phase scan per tile:
//   phase1: local scan (init 0) -> carry; block scan of carries via
//           wave shfl_up with precomputed decay powers (chunk length is
//           uniform, so the carry scan is itself an EMA with coeff a^25);
//   phase2: re-scan from correct incoming state, compute output.
// All global traffic is coalesced float4 via an LDS staging tile.

#define THREADS 256
#define K 25
#define TILE (THREADS * K)      // 6400 floats = 25.6 KB LDS
#define T_LEN 64000
#define NTILES (T_LEN / TILE)   // 10
#define EPS_V 1e-6f

__global__ __launch_bounds__(THREADS)
void dual_ema_hp_kernel(const float* __restrict__ x,
                        const float* __restrict__ p_mu_fast,
                        const float* __restrict__ p_mu_slow,
                        const float* __restrict__ p_mwa,
                        const float* __restrict__ p_mhp,
                        float* __restrict__ out)
{
    __shared__ float tile[TILE];
    __shared__ float aggf[THREADS / 64];
    __shared__ float aggs[THREADS / 64];
    __shared__ float st_f, st_s;   // cross-tile state (written by last thread)

    const int tid  = threadIdx.x;
    const int lane = tid & 63;
    const int wv   = tid >> 6;
    const size_t base = (size_t)blockIdx.x * T_LEN;

    const float mu_f = p_mu_fast[0];
    const float mu_s = p_mu_slow[0];
    const float af = 1.0f - mu_f;
    const float as = 1.0f - mu_s;
    const float wa  = 1.0f / (1.0f + expf(-p_mwa[0]));   // sigmoid(mix_weight_adapt)
    const float wb  = 1.0f - wa;
    const float whp = 1.0f / (1.0f + expf(-p_mhp[0]));   // sigmoid(mix_weight_hp)

    // Decay of one 25-element chunk, and powers for the shuffle scan.
    const float Pf1  = powf(af, (float)K);
    const float Ps1  = powf(as, (float)K);
    const float Pf2  = Pf1 * Pf1,   Ps2  = Ps1 * Ps1;
    const float Pf4  = Pf2 * Pf2,   Ps4  = Ps2 * Ps2;
    const float Pf8  = Pf4 * Pf4,   Ps8  = Ps4 * Ps4;
    const float Pf16 = Pf8 * Pf8,   Ps16 = Ps8 * Ps8;
    const float Pf32 = Pf16 * Pf16, Ps32 = Ps16 * Ps16;
    const float Pf64 = Pf32 * Pf32, Ps64 = Ps32 * Ps32;   // decay of one wave (64 chunks)
    const float Pf_lane = powf(af, (float)(K * lane));    // decay of `lane` chunks
    const float Ps_lane = powf(as, (float)(K * lane));

    float sfr = 0.0f, ssr = 0.0f;   // thread-0's incoming state for this tile

    for (int t = 0; t < NTILES; ++t) {
        __syncthreads();   // protect LDS tile (prev store readers) before overwrite

        // ---- coalesced global -> LDS (float4) ----
        {
            const float4* g4 = (const float4*)(x + base + (size_t)t * TILE);
            float4*       l4 = (float4*)tile;
            for (int idx = tid; idx < TILE / 4; idx += THREADS) l4[idx] = g4[idx];
        }
        __syncthreads();

        if (tid == 0 && t > 0) { sfr = st_f; ssr = st_s; }

        // ---- per-thread chunk into registers, ReLU ----
        float y[K];
#pragma unroll
        for (int i = 0; i < K; ++i) {
            float v = tile[tid * K + i];       // stride 25: 2-way bank alias = free
            y[i] = fmaxf(v, 0.0f);
        }

        // ---- phase 1: local scan -> carry (mf, ms) ----
        float mf, ms;
        {
            float y0 = y[0];
            if (tid == 0) {
                if (t == 0) { mf = y0; ms = y0; }   // EMA init at first sample
                else {
                    mf = fmaf(af, sfr, mu_f * y0);
                    ms = fmaf(as, ssr, mu_s * y0);
                }
            } else {
                mf = mu_f * y0;   // init 0
                ms = mu_s * y0;
            }
#pragma unroll
            for (int i = 1; i < K; ++i) {
                mf = fmaf(af, mf, mu_f * y[i]);
                ms = fmaf(as, ms, mu_s * y[i]);
            }
        }

        // ---- wave inclusive scan of carries (recurrence s_i = P*s_{i-1} + c_i) ----
        float cf = mf, cs = ms;
        {
            float uf, us;
            uf = __shfl_up(cf, 1);  us = __shfl_up(cs, 1);
            if (lane >= 1)  { cf = fmaf(Pf1,  uf, cf); cs = fmaf(Ps1,  us, cs); }
            uf = __shfl_up(cf, 2);  us = __shfl_up(cs, 2);
            if (lane >= 2)  { cf = fmaf(Pf2,  uf, cf); cs = fmaf(Ps2,  us, cs); }
            uf = __shfl_up(cf, 4);  us = __shfl_up(cs, 4);
            if (lane >= 4)  { cf = fmaf(Pf4,  uf, cf); cs = fmaf(Ps4,  us, cs); }
            uf = __shfl_up(cf, 8);  us = __shfl_up(cs, 8);
            if (lane >= 8)  { cf = fmaf(Pf8,  uf, cf); cs = fmaf(Ps8,  us, cs); }
            uf = __shfl_up(cf, 16); us = __shfl_up(cs, 16);
            if (lane >= 16) { cf = fmaf(Pf16, uf, cf); cs = fmaf(Ps16, us, cs); }
            uf = __shfl_up(cf, 32); us = __shfl_up(cs, 32);
            if (lane >= 32) { cf = fmaf(Pf32, uf, cf); cs = fmaf(Ps32, us, cs); }
        }
        if (lane == 63) { aggf[wv] = cf; aggs[wv] = cs; }
        __syncthreads();

        // ---- cross-wave offset + exclusive state for my chunk ----
        float offf = 0.0f, offs = 0.0f;
        for (int w = 0; w < wv; ++w) {
            offf = fmaf(Pf64, offf, aggf[w]);
            offs = fmaf(Ps64, offs, aggs[w]);
        }
        float ef = __shfl_up(cf, 1), es = __shfl_up(cs, 1);
        if (lane == 0) { ef = 0.0f; es = 0.0f; }
        float s_f = fmaf(Pf_lane, offf, ef);   // state entering my chunk
        float s_s = fmaf(Ps_lane, offs, es);

        // next-tile incoming state (state after the whole tile)
        if (tid == THREADS - 1) {
            st_f = fmaf(Pf64, offf, cf);
            st_s = fmaf(Ps64, offs, cs);
        }

        // ---- phase 2: re-scan with correct state, compute output into LDS ----
        {
            float mf2, ms2;
            if (tid == 0) { mf2 = sfr; ms2 = ssr; }
            else          { mf2 = s_f; ms2 = s_s; }
#pragma unroll
            for (int i = 0; i < K; ++i) {
                float yv = y[i];
                if (i == 0 && t == 0 && tid == 0) { mf2 = yv; ms2 = yv; }
                else {
                    mf2 = fmaf(af, mf2, mu_f * yv);
                    ms2 = fmaf(as, ms2, mu_s * yv);
                }
                float M = fmaf(wa, mf2, wb * ms2);
                float o = yv / (EPS_V + M) + whp * (yv - M);
                tile[tid * K + i] = o;
            }
        }
        __syncthreads();

        // ---- coalesced LDS -> global (float4) ----
        {
            float4*       go = (float4*)(out + base + (size_t)t * TILE);
            const float4* l4 = (const float4*)tile;
            for (int idx = tid; idx < TILE / 4; idx += THREADS) go[idx] = l4[idx];
        }
    }
}

extern "C" void kernel_launch(void* const* d_in, const int* in_sizes, int n_in,
                              void* d_out, int out_size, void* d_ws, size_t ws_size,
                              hipStream_t stream) {
    const float* x    = (const float*)d_in[0];
    const float* mu_f = (const float*)d_in[1];
    const float* mu_s = (const float*)d_in[2];
    const float* mwa  = (const float*)d_in[3];
    const float* mhp  = (const float*)d_in[4];
    float* out = (float*)d_out;

    const int rows = in_sizes[0] / T_LEN;   // B*C = 512
    dual_ema_hp_kernel<<<rows, THREADS, 0, stream>>>(x, mu_f, mu_s, mwa, mhp, out);
}